// Round 8
// baseline (263.030 us; speedup 1.0000x reference)
//
#include <hip/hip_runtime.h>

#define N_INPUT 256
#define HS 32

// ---- bucket-sort CSR build params ----
#define BKT_SHIFT 7
#define BKT_NODES 128           // nodes per bucket
#define NBUCK_MAX 800           // LDS sizing; runtime nbuck = ceil(N/128) = 782
#define CAP 2560                // per-bucket edge capacity (mean 2048, sigma ~45 -> +11 sigma)
#define EPB 2048                // edges per S1 block (R14: REVERTED to R12. R13's
                                // EPB=16384 cut S1 to 98 blocks = 1.5 waves/CU ->
                                // 315us straggler tail, occupancy 5.7%. Granularity
                                // must stay fine; parallelism beats line-merging.)

typedef __attribute__((ext_vector_type(8))) short bf16x8;
typedef __attribute__((ext_vector_type(4))) float f32x4;
typedef __attribute__((ext_vector_type(8))) unsigned short u16x8;

// fp32 -> bf16 bits, round-to-nearest-even
__device__ __forceinline__ unsigned short f2bf(float f) {
    unsigned u = __float_as_uint(f);
    unsigned r = u + 0x7FFFu + ((u >> 16) & 1u);
    return (unsigned short)(r >> 16);
}
__device__ __forceinline__ float bf2f(unsigned short u) {
    return __uint_as_float((unsigned)u << 16);
}

// R12 prep: zero gtail + pack the frag-ordered bf16 weights ONCE into
// global Wp (48 KB, L2-resident, shared by all QKV blocks).
__global__ void prep_kernel(int* __restrict__ gtail, int nb,
                            const float* __restrict__ Wq,
                            const float* __restrict__ Wk,
                            const float* __restrict__ Wv,
                            uint4* __restrict__ Wp) {
    int t = threadIdx.x;
    if (blockIdx.x == 0) {
        for (int i = t; i < nb; i += 256) gtail[i] = 0;
        return;
    }
    int c = (int)(blockIdx.x - 1) * 256 + t;  // 0..3071
    int s = c >> 9;
    int tt = (c >> 6) & 7;
    int L = c & 63;
    const float* wm = (s < 2) ? Wq : (s < 4) ? Wk : Wv;
    const float* wsrc = wm + (size_t)(tt * 32 + (L >> 4) * 8) * HS + (s & 1) * 16 + (L & 15);
    unsigned e0 = f2bf(wsrc[0 * HS]) | ((unsigned)f2bf(wsrc[1 * HS]) << 16);
    unsigned e1 = f2bf(wsrc[2 * HS]) | ((unsigned)f2bf(wsrc[3 * HS]) << 16);
    unsigned e2 = f2bf(wsrc[4 * HS]) | ((unsigned)f2bf(wsrc[5 * HS]) << 16);
    unsigned e3 = f2bf(wsrc[6 * HS]) | ((unsigned)f2bf(wsrc[7 * HS]) << 16);
    Wp[c] = make_uint4(e0, e1, e2, e3);
}

// R15 mega kernel: R14 structure (grid-fused S1 || QKV, EPB=2048, %3
// interleave, 4-B packed records) + __launch_bounds__(256, 8). R7 counters:
// VGPR_Count=68, 4 regs over the measured 64-VGPR occupancy cliff (m69:
// waves/CU halve at 64/128/256) -> 16-wave cap, 8 observed, both roles
// latency-starved at 25% occupancy. Forcing 8 waves/EU caps VGPR at 64.
__global__ __launch_bounds__(256, 8) void mega_kernel(
        const float* __restrict__ X, const uint4* __restrict__ Wp,
        const int* __restrict__ src, const int* __restrict__ dst,
        float* __restrict__ Q, unsigned short* __restrict__ KVb,
        int* __restrict__ gtail, unsigned* __restrict__ staging,
        int N, int E, int nb, int s1blocks) {
    __shared__ int sh[NBUCK_MAX];   // per-block bucket histogram
    __shared__ int sbs[NBUCK_MAX];  // this block's base within each bucket
    int tid = threadIdx.x;
    int idx = (int)blockIdx.x;
    bool is_s1 = (idx % 3 == 0) && (idx / 3 < s1blocks);

    if (is_s1) {
        // ---- S1: single-pass bucket partition (rank cached in registers) ----
        int e0 = (idx / 3) * EPB;
        for (int i = tid; i < nb; i += 256) sh[i] = 0;
        __syncthreads();
        int ss[8], dd[8], rr[8];
#pragma unroll
        for (int k = 0; k < 8; ++k) {
            int i = e0 + tid + k * 256;
            ss[k] = -1;
            if (i < E) {
                int s = src[i];
                dd[k] = dst[i];
                ss[k] = s;
                rr[k] = atomicAdd(&sh[s >> BKT_SHIFT], 1);
            }
        }
        __syncthreads();
        // reserve global ranges: one device atomic per (block, nonzero bucket)
        for (int b = tid; b < nb; b += 256) {
            int c = sh[b];
            sbs[b] = c ? atomicAdd(&gtail[b], c) : 0;
        }
        __syncthreads();
        // scatter 4-B packed records into bucket staging (fire-and-forget)
#pragma unroll
        for (int k = 0; k < 8; ++k) {
            if (ss[k] >= 0) {
                int b = ss[k] >> BKT_SHIFT;
                int pos = sbs[b] + rr[k];
                if (pos < CAP)  // +11 sigma; OOB guard only
                    staging[(size_t)b * CAP + pos] =
                        ((unsigned)(ss[k] & (BKT_NODES - 1)) << 17) | (unsigned)dd[k];
            }
        }
        return;
    }

    // ---- QKV projection (MFMA), LDS-free. Q fp32; K,V bf16 interleaved
    // per node: 128-B row of 8 chunks { K[c*4..+3], V[c*4..+3] } so the
    // gather pass fetches K and V with ONE dwordx4 per lane. ----
    int bq = idx - min(idx / 3 + 1, s1blocks);
    int wave = tid >> 6;
    int L = tid & 63;
    int quad = L >> 4;
    int lane16 = L & 15;
    int mt = bq * 4 + wave;
    if (mt * 16 >= N) return;

    const float* xrow = X + (size_t)(mt * 16 + lane16) * N_INPUT + quad * 8;
    bf16x8 afrag[8];
#pragma unroll
    for (int t = 0; t < 8; ++t) {
        float4 a0 = *(const float4*)(xrow + t * 32);
        float4 a1 = *(const float4*)(xrow + t * 32 + 4);
        bf16x8 f;
        f[0] = (short)f2bf(a0.x); f[1] = (short)f2bf(a0.y);
        f[2] = (short)f2bf(a0.z); f[3] = (short)f2bf(a0.w);
        f[4] = (short)f2bf(a1.x); f[5] = (short)f2bf(a1.y);
        f[6] = (short)f2bf(a1.z); f[7] = (short)f2bf(a1.w);
        afrag[t] = f;
    }

#pragma unroll
    for (int s = 0; s < 6; ++s) {
        f32x4 acc = {0.f, 0.f, 0.f, 0.f};
#pragma unroll
        for (int t = 0; t < 8; ++t) {
            bf16x8 bfrag = ((const bf16x8*)Wp)[(s * 8 + t) * 64 + L];
            acc = __builtin_amdgcn_mfma_f32_16x16x32_bf16(afrag[t], bfrag, acc, 0, 0, 0);
        }
        int col = (s & 1) * 16 + lane16;
#pragma unroll
        for (int r = 0; r < 4; ++r) {
            int row = mt * 16 + quad * 4 + r;
            if (s < 2) {
                Q[(size_t)row * HS + col] = acc[r];
            } else {
                size_t pos = (size_t)row * 64 + (size_t)(col >> 2) * 8 +
                             ((s < 4) ? 0 : 4) + (col & 3);
                KVb[pos] = f2bf(acc[r]);
            }
        }
    }
}

// R10 fused S2+aggregation: one block per 128-node bucket; per-node edge
// lists built entirely in LDS; 16 32-lane groups aggregate from LDS.
// R14: 1-deep KV-gather pipeline. R15: __launch_bounds__(512, 8) forces
// VGPR <= 64 (same occupancy-cliff reasoning as mega) so 4 blocks/CU of
// gather-latency-hiding waves fit instead of 2.
__global__ __launch_bounds__(512, 8) void s2_agg_kernel(
        const unsigned* __restrict__ staging, const int* __restrict__ gtail,
        const float* __restrict__ Q, const unsigned short* __restrict__ KVb,
        float* __restrict__ out, int N) {
    __shared__ int ldst[CAP];        // 10 KB sorted dst list
    __shared__ int nh[BKT_NODES];    // per-node count
    __shared__ int nx[BKT_NODES];    // inclusive scan
    __shared__ int rk[BKT_NODES];    // rank
    int b = blockIdx.x;
    int t = threadIdx.x;
    int cnt = min(gtail[b], CAP);
    if (t < BKT_NODES) { nh[t] = 0; rk[t] = 0; }
    __syncthreads();
    // hist pass; stash records in regs (static idx - rule #20)
    unsigned stash[5];
#pragma unroll
    for (int k = 0; k < 5; ++k) {
        int i = t + k * 512;
        if (i < cnt) {
            unsigned e = staging[(size_t)b * CAP + i];
            stash[k] = e;
            atomicAdd(&nh[e >> 17], 1);
        }
    }
    __syncthreads();
    if (t < BKT_NODES) nx[t] = nh[t];
    __syncthreads();
    for (int off = 1; off < BKT_NODES; off <<= 1) {
        int u = (t >= off && t < BKT_NODES) ? nx[t - off] : 0;
        __syncthreads();
        if (t < BKT_NODES) nx[t] += u;
        __syncthreads();
    }
#pragma unroll
    for (int k = 0; k < 5; ++k) {
        int i = t + k * 512;
        if (i < cnt) {
            unsigned e = stash[k];
            int sl = (int)(e >> 17);
            int r = atomicAdd(&rk[sl], 1);  // LDS atomic
            ldst[nx[sl] - nh[sl] + r] = (int)(e & 0x1FFFFu);
        }
    }
    __syncthreads();

    // ---- aggregation: 16 groups of 32 lanes; 4 edge slots x 8 sub-lanes ----
    int lane = t & 31;
    int grp = t >> 5;
    int slot = lane >> 3;
    int sub = lane & 7;
    int node0 = b << BKT_SHIFT;
    for (int ni = grp; ni < BKT_NODES; ni += 16) {
        int n = node0 + ni;
        if (n >= N) continue;
        int end = nx[ni];
        int beg = end - nh[ni];
        float4 qf = *(const float4*)(Q + (size_t)n * HS + sub * 4);
        float4 acc = make_float4(0.f, 0.f, 0.f, 0.f);
        float den = 0.f;
        // 1-deep pipelined edge loop: gather for j+4 issued before compute of j
        int d0 = (beg + slot < end) ? ldst[beg + slot] : 0;
        u16x8 kvc = *(const u16x8*)(KVb + (size_t)d0 * 64 + sub * 8);
        for (int j = beg; j < end; j += 4) {
            bool valid = (j + slot) < end;
            u16x8 kv = kvc;
            int jn = j + 4;
            if (jn < end) {  // group-uniform branch
                int dn = (jn + slot < end) ? ldst[jn + slot] : 0;
                kvc = *(const u16x8*)(KVb + (size_t)dn * 64 + sub * 8);
            }
            float p = qf.x * bf2f(kv[0]) + qf.y * bf2f(kv[1]) +
                      qf.z * bf2f(kv[2]) + qf.w * bf2f(kv[3]);
            p += __shfl_xor(p, 1, 32);
            p += __shfl_xor(p, 2, 32);
            p += __shfl_xor(p, 4, 32);
            float ex = valid ? __expf(p * 0.17677669529663687f) : 0.f;  // 1/sqrt(32)
            den += ex;
            acc.x += ex * bf2f(kv[4]);
            acc.y += ex * bf2f(kv[5]);
            acc.z += ex * bf2f(kv[6]);
            acc.w += ex * bf2f(kv[7]);
        }
        // sum the 4 edge slots (xor over slot bits 3,4)
#pragma unroll
        for (int off = 8; off <= 16; off <<= 1) {
            acc.x += __shfl_xor(acc.x, off, 32);
            acc.y += __shfl_xor(acc.y, off, 32);
            acc.z += __shfl_xor(acc.z, off, 32);
            acc.w += __shfl_xor(acc.w, off, 32);
            den += __shfl_xor(den, off, 32);
        }
        if (lane < 8) {
            float4 o = make_float4(0.f, 0.f, 0.f, 0.f);
            if (end > beg) {
                float rd = 1.f / den;
                o = make_float4(acc.x * rd, acc.y * rd, acc.z * rd, acc.w * rd);
            }
            *(float4*)(out + (size_t)n * HS + lane * 4) = o;
        }
    }
}

extern "C" void kernel_launch(void* const* d_in, const int* in_sizes, int n_in,
                              void* d_out, int out_size, void* d_ws, size_t ws_size,
                              hipStream_t stream) {
    const float* X  = (const float*)d_in[0];
    const int*   ei = (const int*)d_in[1];
    const float* Wq = (const float*)d_in[2];
    const float* Wk = (const float*)d_in[3];
    const float* Wv = (const float*)d_in[4];

    int N = in_sizes[0] / N_INPUT;
    int E = in_sizes[1] / 2;
    const int* src = ei;
    const int* dst = ei + E;

    // ws layout: Q[N*32] fp32 (12.8 MB); KVb[N*64] bf16 interleaved rows
    // (12.8 MB); Wp[3072] uint4 (48 KB); gtail[NBUCK_MAX];
    // staging[nbuck*CAP] 4-B packed records (8 MB). No aliasing.
    float* ws = (float*)d_ws;
    float* Q = ws;
    unsigned short* KVb = (unsigned short*)(Q + (size_t)N * HS);
    uint4* Wp = (uint4*)(KVb + (size_t)N * 64);
    int* gtail = (int*)(Wp + 3072);
    unsigned* staging = (unsigned*)(gtail + NBUCK_MAX);
    float* out = (float*)d_out;

    int nbuck = (N + BKT_NODES - 1) >> BKT_SHIFT;  // 782
    int s1blocks = (E + EPB - 1) / EPB;            // 782
    int mtiles = (N + 15) / 16;
    int qblocks = (mtiles + 3) / 4;                // 1563

    prep_kernel<<<13, 256, 0, stream>>>(gtail, nbuck, Wq, Wk, Wv, Wp);
    mega_kernel<<<s1blocks + qblocks, 256, 0, stream>>>(
        X, Wp, src, dst, Q, KVb, gtail, staging, N, E, nbuck, s1blocks);
    s2_agg_kernel<<<nbuck, 512, 0, stream>>>(staging, gtail, Q, KVb, out, N);
}

// Round 9
// 247.929 us; speedup vs baseline: 1.0609x; 1.0609x over previous
//
#include <hip/hip_runtime.h>

#define N_INPUT 256
#define HS 32

// ---- bucket-sort CSR build params ----
#define BKT_SHIFT 7
#define BKT_NODES 128           // nodes per bucket
#define NBUCK_MAX 800           // LDS sizing; runtime nbuck = ceil(N/128) = 782
#define CAP 2560                // per-bucket edge capacity (mean 2048, sigma ~45 -> +11 sigma)
#define EPB 2048                // edges per S1 block (R14: fine granularity beats
                                // line-merging; R13's EPB=16384 was a 315us straggler)

typedef __attribute__((ext_vector_type(8))) short bf16x8;
typedef __attribute__((ext_vector_type(4))) float f32x4;
typedef __attribute__((ext_vector_type(8))) unsigned short u16x8;

// fp32 -> bf16 bits, round-to-nearest-even
__device__ __forceinline__ unsigned short f2bf(float f) {
    unsigned u = __float_as_uint(f);
    unsigned r = u + 0x7FFFu + ((u >> 16) & 1u);
    return (unsigned short)(r >> 16);
}
__device__ __forceinline__ float bf2f(unsigned short u) {
    return __uint_as_float((unsigned)u << 16);
}

// R12 prep: zero gtail + pack the frag-ordered bf16 weights ONCE into
// global Wp (48 KB, L2-resident, shared by all QKV blocks).
__global__ void prep_kernel(int* __restrict__ gtail, int nb,
                            const float* __restrict__ Wq,
                            const float* __restrict__ Wk,
                            const float* __restrict__ Wv,
                            uint4* __restrict__ Wp) {
    int t = threadIdx.x;
    if (blockIdx.x == 0) {
        for (int i = t; i < nb; i += 256) gtail[i] = 0;
        return;
    }
    int c = (int)(blockIdx.x - 1) * 256 + t;  // 0..3071
    int s = c >> 9;
    int tt = (c >> 6) & 7;
    int L = c & 63;
    const float* wm = (s < 2) ? Wq : (s < 4) ? Wk : Wv;
    const float* wsrc = wm + (size_t)(tt * 32 + (L >> 4) * 8) * HS + (s & 1) * 16 + (L & 15);
    unsigned e0 = f2bf(wsrc[0 * HS]) | ((unsigned)f2bf(wsrc[1 * HS]) << 16);
    unsigned e1 = f2bf(wsrc[2 * HS]) | ((unsigned)f2bf(wsrc[3 * HS]) << 16);
    unsigned e2 = f2bf(wsrc[4 * HS]) | ((unsigned)f2bf(wsrc[5 * HS]) << 16);
    unsigned e3 = f2bf(wsrc[6 * HS]) | ((unsigned)f2bf(wsrc[7 * HS]) << 16);
    Wp[c] = make_uint4(e0, e1, e2, e3);
}

// R16 mega kernel: grid-fused {S1} || {QKV}. R15 lesson: forcing VGPR<=64
// via launch_bounds alone SPILLED (VGPR_Count=32, +70 MB scratch traffic,
// 105us). Fix: REDUCE DEMAND -- QKV loop restructured t-outer/s-inner so
// only ONE afrag (4 regs) is live instead of all 8 (32 regs): peak live
// ~= acc 24 + afrag 4 + bfrag 4 + transients ~ 50 VGPR. launch_bounds
// (256,8) now has headroom -> 8 waves/SIMD without spill.
__global__ __launch_bounds__(256, 8) void mega_kernel(
        const float* __restrict__ X, const uint4* __restrict__ Wp,
        const int* __restrict__ src, const int* __restrict__ dst,
        float* __restrict__ Q, unsigned short* __restrict__ KVb,
        int* __restrict__ gtail, unsigned* __restrict__ staging,
        int N, int E, int nb, int s1blocks) {
    __shared__ int sh[NBUCK_MAX];   // per-block bucket histogram
    __shared__ int sbs[NBUCK_MAX];  // this block's base within each bucket
    int tid = threadIdx.x;
    int idx = (int)blockIdx.x;
    bool is_s1 = (idx % 3 == 0) && (idx / 3 < s1blocks);

    if (is_s1) {
        // ---- S1: single-pass bucket partition (rank cached in registers) ----
        int e0 = (idx / 3) * EPB;
        for (int i = tid; i < nb; i += 256) sh[i] = 0;
        __syncthreads();
        int ss[8], dd[8], rr[8];
#pragma unroll
        for (int k = 0; k < 8; ++k) {
            int i = e0 + tid + k * 256;
            ss[k] = -1;
            if (i < E) {
                int s = src[i];
                dd[k] = dst[i];
                ss[k] = s;
                rr[k] = atomicAdd(&sh[s >> BKT_SHIFT], 1);
            }
        }
        __syncthreads();
        // reserve global ranges: one device atomic per (block, nonzero bucket)
        for (int b = tid; b < nb; b += 256) {
            int c = sh[b];
            sbs[b] = c ? atomicAdd(&gtail[b], c) : 0;
        }
        __syncthreads();
        // scatter 4-B packed records into bucket staging (fire-and-forget)
#pragma unroll
        for (int k = 0; k < 8; ++k) {
            if (ss[k] >= 0) {
                int b = ss[k] >> BKT_SHIFT;
                int pos = sbs[b] + rr[k];
                if (pos < CAP)  // +11 sigma; OOB guard only
                    staging[(size_t)b * CAP + pos] =
                        ((unsigned)(ss[k] & (BKT_NODES - 1)) << 17) | (unsigned)dd[k];
            }
        }
        return;
    }

    // ---- QKV projection (MFMA), LDS-free, t-outer/s-inner. Q fp32; K,V
    // bf16 interleaved per node: 128-B row of 8 chunks { K[c*4..+3],
    // V[c*4..+3] } so the gather pass fetches K and V with ONE dwordx4. ----
    int bq = idx - min(idx / 3 + 1, s1blocks);
    int wave = tid >> 6;
    int L = tid & 63;
    int quad = L >> 4;
    int lane16 = L & 15;
    int mt = bq * 4 + wave;
    if (mt * 16 >= N) return;

    const float* xrow = X + (size_t)(mt * 16 + lane16) * N_INPUT + quad * 8;
    f32x4 acc[6];
#pragma unroll
    for (int s = 0; s < 6; ++s) acc[s] = (f32x4){0.f, 0.f, 0.f, 0.f};

#pragma unroll
    for (int t = 0; t < 8; ++t) {
        float4 a0 = *(const float4*)(xrow + t * 32);
        float4 a1 = *(const float4*)(xrow + t * 32 + 4);
        bf16x8 f;
        f[0] = (short)f2bf(a0.x); f[1] = (short)f2bf(a0.y);
        f[2] = (short)f2bf(a0.z); f[3] = (short)f2bf(a0.w);
        f[4] = (short)f2bf(a1.x); f[5] = (short)f2bf(a1.y);
        f[6] = (short)f2bf(a1.z); f[7] = (short)f2bf(a1.w);
#pragma unroll
        for (int s = 0; s < 6; ++s) {
            bf16x8 bfrag = ((const bf16x8*)Wp)[(s * 8 + t) * 64 + L];
            acc[s] = __builtin_amdgcn_mfma_f32_16x16x32_bf16(f, bfrag, acc[s], 0, 0, 0);
        }
    }

#pragma unroll
    for (int s = 0; s < 6; ++s) {
        int col = (s & 1) * 16 + lane16;
#pragma unroll
        for (int r = 0; r < 4; ++r) {
            int row = mt * 16 + quad * 4 + r;
            if (s < 2) {
                Q[(size_t)row * HS + col] = acc[s][r];
            } else {
                size_t pos = (size_t)row * 64 + (size_t)(col >> 2) * 8 +
                             ((s < 4) ? 0 : 4) + (col & 3);
                KVb[pos] = f2bf(acc[s][r]);
            }
        }
    }
}

// R10 fused S2+aggregation (R14 config restored: plain launch_bounds(512),
// the R15 min-waves experiment is reverted -- one variable at a time).
// One block per 128-node bucket; per-node edge lists built entirely in
// LDS; 16 32-lane groups aggregate from LDS; 1-deep KV-gather pipeline.
__global__ __launch_bounds__(512) void s2_agg_kernel(
        const unsigned* __restrict__ staging, const int* __restrict__ gtail,
        const float* __restrict__ Q, const unsigned short* __restrict__ KVb,
        float* __restrict__ out, int N) {
    __shared__ int ldst[CAP];        // 10 KB sorted dst list
    __shared__ int nh[BKT_NODES];    // per-node count
    __shared__ int nx[BKT_NODES];    // inclusive scan
    __shared__ int rk[BKT_NODES];    // rank
    int b = blockIdx.x;
    int t = threadIdx.x;
    int cnt = min(gtail[b], CAP);
    if (t < BKT_NODES) { nh[t] = 0; rk[t] = 0; }
    __syncthreads();
    // hist pass; stash records in regs (static idx - rule #20)
    unsigned stash[5];
#pragma unroll
    for (int k = 0; k < 5; ++k) {
        int i = t + k * 512;
        if (i < cnt) {
            unsigned e = staging[(size_t)b * CAP + i];
            stash[k] = e;
            atomicAdd(&nh[e >> 17], 1);
        }
    }
    __syncthreads();
    if (t < BKT_NODES) nx[t] = nh[t];
    __syncthreads();
    for (int off = 1; off < BKT_NODES; off <<= 1) {
        int u = (t >= off && t < BKT_NODES) ? nx[t - off] : 0;
        __syncthreads();
        if (t < BKT_NODES) nx[t] += u;
        __syncthreads();
    }
#pragma unroll
    for (int k = 0; k < 5; ++k) {
        int i = t + k * 512;
        if (i < cnt) {
            unsigned e = stash[k];
            int sl = (int)(e >> 17);
            int r = atomicAdd(&rk[sl], 1);  // LDS atomic
            ldst[nx[sl] - nh[sl] + r] = (int)(e & 0x1FFFFu);
        }
    }
    __syncthreads();

    // ---- aggregation: 16 groups of 32 lanes; 4 edge slots x 8 sub-lanes ----
    int lane = t & 31;
    int grp = t >> 5;
    int slot = lane >> 3;
    int sub = lane & 7;
    int node0 = b << BKT_SHIFT;
    for (int ni = grp; ni < BKT_NODES; ni += 16) {
        int n = node0 + ni;
        if (n >= N) continue;
        int end = nx[ni];
        int beg = end - nh[ni];
        float4 qf = *(const float4*)(Q + (size_t)n * HS + sub * 4);
        float4 acc = make_float4(0.f, 0.f, 0.f, 0.f);
        float den = 0.f;
        // 1-deep pipelined edge loop: gather for j+4 issued before compute of j
        int d0 = (beg + slot < end) ? ldst[beg + slot] : 0;
        u16x8 kvc = *(const u16x8*)(KVb + (size_t)d0 * 64 + sub * 8);
        for (int j = beg; j < end; j += 4) {
            bool valid = (j + slot) < end;
            u16x8 kv = kvc;
            int jn = j + 4;
            if (jn < end) {  // group-uniform branch
                int dn = (jn + slot < end) ? ldst[jn + slot] : 0;
                kvc = *(const u16x8*)(KVb + (size_t)dn * 64 + sub * 8);
            }
            float p = qf.x * bf2f(kv[0]) + qf.y * bf2f(kv[1]) +
                      qf.z * bf2f(kv[2]) + qf.w * bf2f(kv[3]);
            p += __shfl_xor(p, 1, 32);
            p += __shfl_xor(p, 2, 32);
            p += __shfl_xor(p, 4, 32);
            float ex = valid ? __expf(p * 0.17677669529663687f) : 0.f;  // 1/sqrt(32)
            den += ex;
            acc.x += ex * bf2f(kv[4]);
            acc.y += ex * bf2f(kv[5]);
            acc.z += ex * bf2f(kv[6]);
            acc.w += ex * bf2f(kv[7]);
        }
        // sum the 4 edge slots (xor over slot bits 3,4)
#pragma unroll
        for (int off = 8; off <= 16; off <<= 1) {
            acc.x += __shfl_xor(acc.x, off, 32);
            acc.y += __shfl_xor(acc.y, off, 32);
            acc.z += __shfl_xor(acc.z, off, 32);
            acc.w += __shfl_xor(acc.w, off, 32);
            den += __shfl_xor(den, off, 32);
        }
        if (lane < 8) {
            float4 o = make_float4(0.f, 0.f, 0.f, 0.f);
            if (end > beg) {
                float rd = 1.f / den;
                o = make_float4(acc.x * rd, acc.y * rd, acc.z * rd, acc.w * rd);
            }
            *(float4*)(out + (size_t)n * HS + lane * 4) = o;
        }
    }
}

extern "C" void kernel_launch(void* const* d_in, const int* in_sizes, int n_in,
                              void* d_out, int out_size, void* d_ws, size_t ws_size,
                              hipStream_t stream) {
    const float* X  = (const float*)d_in[0];
    const int*   ei = (const int*)d_in[1];
    const float* Wq = (const float*)d_in[2];
    const float* Wk = (const float*)d_in[3];
    const float* Wv = (const float*)d_in[4];

    int N = in_sizes[0] / N_INPUT;
    int E = in_sizes[1] / 2;
    const int* src = ei;
    const int* dst = ei + E;

    // ws layout: Q[N*32] fp32 (12.8 MB); KVb[N*64] bf16 interleaved rows
    // (12.8 MB); Wp[3072] uint4 (48 KB); gtail[NBUCK_MAX];
    // staging[nbuck*CAP] 4-B packed records (8 MB). No aliasing.
    float* ws = (float*)d_ws;
    float* Q = ws;
    unsigned short* KVb = (unsigned short*)(Q + (size_t)N * HS);
    uint4* Wp = (uint4*)(KVb + (size_t)N * 64);
    int* gtail = (int*)(Wp + 3072);
    unsigned* staging = (unsigned*)(gtail + NBUCK_MAX);
    float* out = (float*)d_out;

    int nbuck = (N + BKT_NODES - 1) >> BKT_SHIFT;  // 782
    int s1blocks = (E + EPB - 1) / EPB;            // 782
    int mtiles = (N + 15) / 16;
    int qblocks = (mtiles + 3) / 4;                // 1563

    prep_kernel<<<13, 256, 0, stream>>>(gtail, nbuck, Wq, Wk, Wv, Wp);
    mega_kernel<<<s1blocks + qblocks, 256, 0, stream>>>(
        X, Wp, src, dst, Q, KVb, gtail, staging, N, E, nbuck, s1blocks);
    s2_agg_kernel<<<nbuck, 512, 0, stream>>>(staging, gtail, Q, KVb, out, N);
}

// Round 10
// 235.151 us; speedup vs baseline: 1.1186x; 1.0543x over previous
//
#include <hip/hip_runtime.h>

#define N_INPUT 256
#define HS 32

// ---- bucket-sort CSR build params ----
#define BKT_SHIFT 7
#define BKT_NODES 128           // nodes per bucket
#define NBUCK_MAX 800           // LDS sizing; runtime nbuck = ceil(N/128) = 782
#define CAP 2560                // per-bucket edge capacity (mean 2048, sigma ~45 -> +11 sigma)
#define EPB 2048                // edges per S1 block (R14: fine granularity beats
                                // line-merging; R13's EPB=16384 was a 315us straggler)

typedef __attribute__((ext_vector_type(8))) short bf16x8;
typedef __attribute__((ext_vector_type(4))) float f32x4;
typedef __attribute__((ext_vector_type(8))) unsigned short u16x8;

// fp32 -> bf16 bits, round-to-nearest-even
__device__ __forceinline__ unsigned short f2bf(float f) {
    unsigned u = __float_as_uint(f);
    unsigned r = u + 0x7FFFu + ((u >> 16) & 1u);
    return (unsigned short)(r >> 16);
}
__device__ __forceinline__ float bf2f(unsigned short u) {
    return __uint_as_float((unsigned)u << 16);
}

// R12 prep: zero gtail + pack the frag-ordered bf16 weights ONCE into
// global Wp (48 KB, L2-resident, shared by all QKV blocks).
__global__ void prep_kernel(int* __restrict__ gtail, int nb,
                            const float* __restrict__ Wq,
                            const float* __restrict__ Wk,
                            const float* __restrict__ Wv,
                            uint4* __restrict__ Wp) {
    int t = threadIdx.x;
    if (blockIdx.x == 0) {
        for (int i = t; i < nb; i += 256) gtail[i] = 0;
        return;
    }
    int c = (int)(blockIdx.x - 1) * 256 + t;  // 0..3071
    int s = c >> 9;
    int tt = (c >> 6) & 7;
    int L = c & 63;
    const float* wm = (s < 2) ? Wq : (s < 4) ? Wk : Wv;
    const float* wsrc = wm + (size_t)(tt * 32 + (L >> 4) * 8) * HS + (s & 1) * 16 + (L & 15);
    unsigned e0 = f2bf(wsrc[0 * HS]) | ((unsigned)f2bf(wsrc[1 * HS]) << 16);
    unsigned e1 = f2bf(wsrc[2 * HS]) | ((unsigned)f2bf(wsrc[3 * HS]) << 16);
    unsigned e2 = f2bf(wsrc[4 * HS]) | ((unsigned)f2bf(wsrc[5 * HS]) << 16);
    unsigned e3 = f2bf(wsrc[6 * HS]) | ((unsigned)f2bf(wsrc[7 * HS]) << 16);
    Wp[c] = make_uint4(e0, e1, e2, e3);
}

// R17 mega kernel: grid-fused {S1} || {QKV}, t-outer/s-inner QKV loop,
// NO min-waves bound. R15/R16 evidence: __launch_bounds__(256,8) makes
// the allocator SPILL to meet the cap (WRITE +13..+53 MB, mega 90-105us)
// rather than economize. t-outer demand is ~50-56 VGPR (acc 24 + one
// afrag 4 + bfrag 4 + transients); uncapped, the allocator never spills.
// If it lands <=64 we cross the m69 occupancy cliff (16->32 waves/CU);
// if 65-70, R14 parity -- bounded downside either way.
__global__ __launch_bounds__(256) void mega_kernel(
        const float* __restrict__ X, const uint4* __restrict__ Wp,
        const int* __restrict__ src, const int* __restrict__ dst,
        float* __restrict__ Q, unsigned short* __restrict__ KVb,
        int* __restrict__ gtail, unsigned* __restrict__ staging,
        int N, int E, int nb, int s1blocks) {
    __shared__ int sh[NBUCK_MAX];   // per-block bucket histogram
    __shared__ int sbs[NBUCK_MAX];  // this block's base within each bucket
    int tid = threadIdx.x;
    int idx = (int)blockIdx.x;
    bool is_s1 = (idx % 3 == 0) && (idx / 3 < s1blocks);

    if (is_s1) {
        // ---- S1: single-pass bucket partition (rank cached in registers) ----
        int e0 = (idx / 3) * EPB;
        for (int i = tid; i < nb; i += 256) sh[i] = 0;
        __syncthreads();
        int ss[8], dd[8], rr[8];
#pragma unroll
        for (int k = 0; k < 8; ++k) {
            int i = e0 + tid + k * 256;
            ss[k] = -1;
            if (i < E) {
                int s = src[i];
                dd[k] = dst[i];
                ss[k] = s;
                rr[k] = atomicAdd(&sh[s >> BKT_SHIFT], 1);
            }
        }
        __syncthreads();
        // reserve global ranges: one device atomic per (block, nonzero bucket)
        for (int b = tid; b < nb; b += 256) {
            int c = sh[b];
            sbs[b] = c ? atomicAdd(&gtail[b], c) : 0;
        }
        __syncthreads();
        // scatter 4-B packed records into bucket staging (fire-and-forget)
#pragma unroll
        for (int k = 0; k < 8; ++k) {
            if (ss[k] >= 0) {
                int b = ss[k] >> BKT_SHIFT;
                int pos = sbs[b] + rr[k];
                if (pos < CAP)  // +11 sigma; OOB guard only
                    staging[(size_t)b * CAP + pos] =
                        ((unsigned)(ss[k] & (BKT_NODES - 1)) << 17) | (unsigned)dd[k];
            }
        }
        return;
    }

    // ---- QKV projection (MFMA), LDS-free, t-outer/s-inner. Q fp32; K,V
    // bf16 interleaved per node: 128-B row of 8 chunks { K[c*4..+3],
    // V[c*4..+3] } so the gather pass fetches K and V with ONE dwordx4. ----
    int bq = idx - min(idx / 3 + 1, s1blocks);
    int wave = tid >> 6;
    int L = tid & 63;
    int quad = L >> 4;
    int lane16 = L & 15;
    int mt = bq * 4 + wave;
    if (mt * 16 >= N) return;

    const float* xrow = X + (size_t)(mt * 16 + lane16) * N_INPUT + quad * 8;
    f32x4 acc[6];
#pragma unroll
    for (int s = 0; s < 6; ++s) acc[s] = (f32x4){0.f, 0.f, 0.f, 0.f};

#pragma unroll
    for (int t = 0; t < 8; ++t) {
        float4 a0 = *(const float4*)(xrow + t * 32);
        float4 a1 = *(const float4*)(xrow + t * 32 + 4);
        bf16x8 f;
        f[0] = (short)f2bf(a0.x); f[1] = (short)f2bf(a0.y);
        f[2] = (short)f2bf(a0.z); f[3] = (short)f2bf(a0.w);
        f[4] = (short)f2bf(a1.x); f[5] = (short)f2bf(a1.y);
        f[6] = (short)f2bf(a1.z); f[7] = (short)f2bf(a1.w);
#pragma unroll
        for (int s = 0; s < 6; ++s) {
            bf16x8 bfrag = ((const bf16x8*)Wp)[(s * 8 + t) * 64 + L];
            acc[s] = __builtin_amdgcn_mfma_f32_16x16x32_bf16(f, bfrag, acc[s], 0, 0, 0);
        }
    }

#pragma unroll
    for (int s = 0; s < 6; ++s) {
        int col = (s & 1) * 16 + lane16;
#pragma unroll
        for (int r = 0; r < 4; ++r) {
            int row = mt * 16 + quad * 4 + r;
            if (s < 2) {
                Q[(size_t)row * HS + col] = acc[s][r];
            } else {
                size_t pos = (size_t)row * 64 + (size_t)(col >> 2) * 8 +
                             ((s < 4) ? 0 : 4) + (col & 3);
                KVb[pos] = f2bf(acc[s][r]);
            }
        }
    }
}

// R10 fused S2+aggregation (R14 config: plain launch_bounds(512)).
// One block per 128-node bucket; per-node edge lists built entirely in
// LDS; 16 32-lane groups aggregate from LDS; 1-deep KV-gather pipeline.
__global__ __launch_bounds__(512) void s2_agg_kernel(
        const unsigned* __restrict__ staging, const int* __restrict__ gtail,
        const float* __restrict__ Q, const unsigned short* __restrict__ KVb,
        float* __restrict__ out, int N) {
    __shared__ int ldst[CAP];        // 10 KB sorted dst list
    __shared__ int nh[BKT_NODES];    // per-node count
    __shared__ int nx[BKT_NODES];    // inclusive scan
    __shared__ int rk[BKT_NODES];    // rank
    int b = blockIdx.x;
    int t = threadIdx.x;
    int cnt = min(gtail[b], CAP);
    if (t < BKT_NODES) { nh[t] = 0; rk[t] = 0; }
    __syncthreads();
    // hist pass; stash records in regs (static idx - rule #20)
    unsigned stash[5];
#pragma unroll
    for (int k = 0; k < 5; ++k) {
        int i = t + k * 512;
        if (i < cnt) {
            unsigned e = staging[(size_t)b * CAP + i];
            stash[k] = e;
            atomicAdd(&nh[e >> 17], 1);
        }
    }
    __syncthreads();
    if (t < BKT_NODES) nx[t] = nh[t];
    __syncthreads();
    for (int off = 1; off < BKT_NODES; off <<= 1) {
        int u = (t >= off && t < BKT_NODES) ? nx[t - off] : 0;
        __syncthreads();
        if (t < BKT_NODES) nx[t] += u;
        __syncthreads();
    }
#pragma unroll
    for (int k = 0; k < 5; ++k) {
        int i = t + k * 512;
        if (i < cnt) {
            unsigned e = stash[k];
            int sl = (int)(e >> 17);
            int r = atomicAdd(&rk[sl], 1);  // LDS atomic
            ldst[nx[sl] - nh[sl] + r] = (int)(e & 0x1FFFFu);
        }
    }
    __syncthreads();

    // ---- aggregation: 16 groups of 32 lanes; 4 edge slots x 8 sub-lanes ----
    int lane = t & 31;
    int grp = t >> 5;
    int slot = lane >> 3;
    int sub = lane & 7;
    int node0 = b << BKT_SHIFT;
    for (int ni = grp; ni < BKT_NODES; ni += 16) {
        int n = node0 + ni;
        if (n >= N) continue;
        int end = nx[ni];
        int beg = end - nh[ni];
        float4 qf = *(const float4*)(Q + (size_t)n * HS + sub * 4);
        float4 acc = make_float4(0.f, 0.f, 0.f, 0.f);
        float den = 0.f;
        // 1-deep pipelined edge loop: gather for j+4 issued before compute of j
        int d0 = (beg + slot < end) ? ldst[beg + slot] : 0;
        u16x8 kvc = *(const u16x8*)(KVb + (size_t)d0 * 64 + sub * 8);
        for (int j = beg; j < end; j += 4) {
            bool valid = (j + slot) < end;
            u16x8 kv = kvc;
            int jn = j + 4;
            if (jn < end) {  // group-uniform branch
                int dn = (jn + slot < end) ? ldst[jn + slot] : 0;
                kvc = *(const u16x8*)(KVb + (size_t)dn * 64 + sub * 8);
            }
            float p = qf.x * bf2f(kv[0]) + qf.y * bf2f(kv[1]) +
                      qf.z * bf2f(kv[2]) + qf.w * bf2f(kv[3]);
            p += __shfl_xor(p, 1, 32);
            p += __shfl_xor(p, 2, 32);
            p += __shfl_xor(p, 4, 32);
            float ex = valid ? __expf(p * 0.17677669529663687f) : 0.f;  // 1/sqrt(32)
            den += ex;
            acc.x += ex * bf2f(kv[4]);
            acc.y += ex * bf2f(kv[5]);
            acc.z += ex * bf2f(kv[6]);
            acc.w += ex * bf2f(kv[7]);
        }
        // sum the 4 edge slots (xor over slot bits 3,4)
#pragma unroll
        for (int off = 8; off <= 16; off <<= 1) {
            acc.x += __shfl_xor(acc.x, off, 32);
            acc.y += __shfl_xor(acc.y, off, 32);
            acc.z += __shfl_xor(acc.z, off, 32);
            acc.w += __shfl_xor(acc.w, off, 32);
            den += __shfl_xor(den, off, 32);
        }
        if (lane < 8) {
            float4 o = make_float4(0.f, 0.f, 0.f, 0.f);
            if (end > beg) {
                float rd = 1.f / den;
                o = make_float4(acc.x * rd, acc.y * rd, acc.z * rd, acc.w * rd);
            }
            *(float4*)(out + (size_t)n * HS + lane * 4) = o;
        }
    }
}

extern "C" void kernel_launch(void* const* d_in, const int* in_sizes, int n_in,
                              void* d_out, int out_size, void* d_ws, size_t ws_size,
                              hipStream_t stream) {
    const float* X  = (const float*)d_in[0];
    const int*   ei = (const int*)d_in[1];
    const float* Wq = (const float*)d_in[2];
    const float* Wk = (const float*)d_in[3];
    const float* Wv = (const float*)d_in[4];

    int N = in_sizes[0] / N_INPUT;
    int E = in_sizes[1] / 2;
    const int* src = ei;
    const int* dst = ei + E;

    // ws layout: Q[N*32] fp32 (12.8 MB); KVb[N*64] bf16 interleaved rows
    // (12.8 MB); Wp[3072] uint4 (48 KB); gtail[NBUCK_MAX];
    // staging[nbuck*CAP] 4-B packed records (8 MB). No aliasing.
    float* ws = (float*)d_ws;
    float* Q = ws;
    unsigned short* KVb = (unsigned short*)(Q + (size_t)N * HS);
    uint4* Wp = (uint4*)(KVb + (size_t)N * 64);
    int* gtail = (int*)(Wp + 3072);
    unsigned* staging = (unsigned*)(gtail + NBUCK_MAX);
    float* out = (float*)d_out;

    int nbuck = (N + BKT_NODES - 1) >> BKT_SHIFT;  // 782
    int s1blocks = (E + EPB - 1) / EPB;            // 782
    int mtiles = (N + 15) / 16;
    int qblocks = (mtiles + 3) / 4;                // 1563

    prep_kernel<<<13, 256, 0, stream>>>(gtail, nbuck, Wq, Wk, Wv, Wp);
    mega_kernel<<<s1blocks + qblocks, 256, 0, stream>>>(
        X, Wp, src, dst, Q, KVb, gtail, staging, N, E, nbuck, s1blocks);
    s2_agg_kernel<<<nbuck, 512, 0, stream>>>(staging, gtail, Q, KVb, out, N);
}

// Round 11
// 228.150 us; speedup vs baseline: 1.1529x; 1.0307x over previous
//
#include <hip/hip_runtime.h>

#define N_INPUT 256
#define HS 32

// ---- bucket-sort CSR build params ----
#define BKT_SHIFT 7
#define BKT_NODES 128           // nodes per bucket
#define NBUCK_MAX 800           // LDS sizing; runtime nbuck = ceil(N/128) = 782
#define CAP 2560                // per-bucket total capacity (mean 2048, +11 sigma)
#define NREP 8                  // R18: gtail/staging replicas (contention 782 -> ~98)
#define CAPR 416                // per-(bucket,replica) capacity (mean 256, +10 sigma)
#define EPB 2048                // edges per S1 block (R14: fine granularity wins)

typedef __attribute__((ext_vector_type(8))) short bf16x8;
typedef __attribute__((ext_vector_type(4))) float f32x4;
typedef __attribute__((ext_vector_type(8))) unsigned short u16x8;

// fp32 -> bf16 bits, round-to-nearest-even
__device__ __forceinline__ unsigned short f2bf(float f) {
    unsigned u = __float_as_uint(f);
    unsigned r = u + 0x7FFFu + ((u >> 16) & 1u);
    return (unsigned short)(r >> 16);
}
__device__ __forceinline__ float bf2f(unsigned short u) {
    return __uint_as_float((unsigned)u << 16);
}

// R12 prep: zero gtail replicas + pack the frag-ordered bf16 weights ONCE
// into global Wp (48 KB, L2-resident, shared by all QKV blocks).
__global__ void prep_kernel(int* __restrict__ gtail, int nb,
                            const float* __restrict__ Wq,
                            const float* __restrict__ Wk,
                            const float* __restrict__ Wv,
                            uint4* __restrict__ Wp) {
    int t = threadIdx.x;
    if (blockIdx.x == 0) {
        for (int i = t; i < NREP * NBUCK_MAX; i += 256) gtail[i] = 0;
        return;
    }
    int c = (int)(blockIdx.x - 1) * 256 + t;  // 0..3071
    int s = c >> 9;
    int tt = (c >> 6) & 7;
    int L = c & 63;
    const float* wm = (s < 2) ? Wq : (s < 4) ? Wk : Wv;
    const float* wsrc = wm + (size_t)(tt * 32 + (L >> 4) * 8) * HS + (s & 1) * 16 + (L & 15);
    unsigned e0 = f2bf(wsrc[0 * HS]) | ((unsigned)f2bf(wsrc[1 * HS]) << 16);
    unsigned e1 = f2bf(wsrc[2 * HS]) | ((unsigned)f2bf(wsrc[3 * HS]) << 16);
    unsigned e2 = f2bf(wsrc[4 * HS]) | ((unsigned)f2bf(wsrc[5 * HS]) << 16);
    unsigned e3 = f2bf(wsrc[6 * HS]) | ((unsigned)f2bf(wsrc[7 * HS]) << 16);
    Wp[c] = make_uint4(e0, e1, e2, e3);
}

// R18 mega kernel: grid-fused {S1} || {QKV}. QKV reverted to R14's
// s-outer/t-inner loop (R17 A/B: t-outer = 78us vs 69.5 -- preloading all
// 8 afrag keeps 8 X-loads in flight; MLP on the X stream beats register
// economy; occupancy-cliff theory falsified, VGPR 56 + 32% occ was SLOWER).
// New: (a) NREP=8 gtail replicas -- per-address device-atomic contention
// depth 782 -> ~98; (b) non-temporal X loads -- the 102 MB single-read X
// stream no longer evicts S1's partially-filled staging lines from L2.
__global__ __launch_bounds__(256) void mega_kernel(
        const float* __restrict__ X, const uint4* __restrict__ Wp,
        const int* __restrict__ src, const int* __restrict__ dst,
        float* __restrict__ Q, unsigned short* __restrict__ KVb,
        int* __restrict__ gtail, unsigned* __restrict__ staging,
        int N, int E, int nb, int s1blocks) {
    __shared__ int sh[NBUCK_MAX];   // per-block bucket histogram
    __shared__ int sbs[NBUCK_MAX];  // this block's base within each bucket replica
    int tid = threadIdx.x;
    int idx = (int)blockIdx.x;
    bool is_s1 = (idx % 3 == 0) && (idx / 3 < s1blocks);

    if (is_s1) {
        // ---- S1: single-pass bucket partition (rank cached in registers) ----
        int sb = idx / 3;
        int rep = sb & (NREP - 1);
        int e0 = sb * EPB;
        for (int i = tid; i < nb; i += 256) sh[i] = 0;
        __syncthreads();
        int ss[8], dd[8], rr[8];
#pragma unroll
        for (int k = 0; k < 8; ++k) {
            int i = e0 + tid + k * 256;
            ss[k] = -1;
            if (i < E) {
                int s = src[i];
                dd[k] = dst[i];
                ss[k] = s;
                rr[k] = atomicAdd(&sh[s >> BKT_SHIFT], 1);
            }
        }
        __syncthreads();
        // reserve ranges in this block's replica: ~98-deep contention, not 782
        for (int b = tid; b < nb; b += 256) {
            int c = sh[b];
            sbs[b] = c ? atomicAdd(&gtail[rep * NBUCK_MAX + b], c) : 0;
        }
        __syncthreads();
        // scatter 4-B packed records into (bucket, replica) staging region
#pragma unroll
        for (int k = 0; k < 8; ++k) {
            if (ss[k] >= 0) {
                int b = ss[k] >> BKT_SHIFT;
                int pos = sbs[b] + rr[k];
                if (pos < CAPR)  // +10 sigma; OOB guard only
                    staging[((size_t)b * NREP + rep) * CAPR + pos] =
                        ((unsigned)(ss[k] & (BKT_NODES - 1)) << 17) | (unsigned)dd[k];
            }
        }
        return;
    }

    // ---- QKV projection (MFMA), LDS-free, s-outer/t-inner (R14). Q fp32;
    // K,V bf16 interleaved per node: 128-B row of 8 chunks { K[c*4..+3],
    // V[c*4..+3] } so the gather pass fetches K and V with ONE dwordx4. ----
    int bq = idx - min(idx / 3 + 1, s1blocks);
    int wave = tid >> 6;
    int L = tid & 63;
    int quad = L >> 4;
    int lane16 = L & 15;
    int mt = bq * 4 + wave;
    if (mt * 16 >= N) return;

    const float* xrow = X + (size_t)(mt * 16 + lane16) * N_INPUT + quad * 8;
    bf16x8 afrag[8];
#pragma unroll
    for (int t = 0; t < 8; ++t) {
        f32x4 a0 = __builtin_nontemporal_load((const f32x4*)(xrow + t * 32));
        f32x4 a1 = __builtin_nontemporal_load((const f32x4*)(xrow + t * 32 + 4));
        bf16x8 f;
        f[0] = (short)f2bf(a0[0]); f[1] = (short)f2bf(a0[1]);
        f[2] = (short)f2bf(a0[2]); f[3] = (short)f2bf(a0[3]);
        f[4] = (short)f2bf(a1[0]); f[5] = (short)f2bf(a1[1]);
        f[6] = (short)f2bf(a1[2]); f[7] = (short)f2bf(a1[3]);
        afrag[t] = f;
    }

#pragma unroll
    for (int s = 0; s < 6; ++s) {
        f32x4 acc = {0.f, 0.f, 0.f, 0.f};
#pragma unroll
        for (int t = 0; t < 8; ++t) {
            bf16x8 bfrag = ((const bf16x8*)Wp)[(s * 8 + t) * 64 + L];
            acc = __builtin_amdgcn_mfma_f32_16x16x32_bf16(afrag[t], bfrag, acc, 0, 0, 0);
        }
        int col = (s & 1) * 16 + lane16;
#pragma unroll
        for (int r = 0; r < 4; ++r) {
            int row = mt * 16 + quad * 4 + r;
            if (s < 2) {
                Q[(size_t)row * HS + col] = acc[r];
            } else {
                size_t pos = (size_t)row * 64 + (size_t)(col >> 2) * 8 +
                             ((s < 4) ? 0 : 4) + (col & 3);
                KVb[pos] = f2bf(acc[r]);
            }
        }
    }
}

// R10 fused S2+aggregation: one block per 128-node bucket; per-node edge
// lists built entirely in LDS; 16 32-lane groups aggregate from LDS;
// 1-deep KV-gather pipeline. R18: reads NREP replica runs per bucket;
// register stash replaced by a two-pass (hist, place) over L2-hot staging.
__global__ __launch_bounds__(512) void s2_agg_kernel(
        const unsigned* __restrict__ staging, const int* __restrict__ gtail,
        const float* __restrict__ Q, const unsigned short* __restrict__ KVb,
        float* __restrict__ out, int N) {
    __shared__ int ldst[CAP];        // 10 KB sorted dst list
    __shared__ int nh[BKT_NODES];    // per-node count
    __shared__ int nx[BKT_NODES];    // inclusive scan
    __shared__ int rk[BKT_NODES];    // rank
    int b = blockIdx.x;
    int t = threadIdx.x;
    // replica run lengths (wave-uniform broadcast loads; clamp total to CAP)
    int cnt_r[NREP];
    int total = 0;
#pragma unroll
    for (int r = 0; r < NREP; ++r) {
        int c = min(gtail[r * NBUCK_MAX + b], CAPR);
        c = min(c, CAP - total);
        cnt_r[r] = c;
        total += c;
    }
    if (t < BKT_NODES) { nh[t] = 0; rk[t] = 0; }
    __syncthreads();
    // pass 1: per-node histogram
#pragma unroll
    for (int r = 0; r < NREP; ++r) {
        const unsigned* sg = staging + ((size_t)b * NREP + r) * CAPR;
        for (int i = t; i < cnt_r[r]; i += 512)
            atomicAdd(&nh[sg[i] >> 17], 1);
    }
    __syncthreads();
    if (t < BKT_NODES) nx[t] = nh[t];
    __syncthreads();
    for (int off = 1; off < BKT_NODES; off <<= 1) {
        int u = (t >= off && t < BKT_NODES) ? nx[t - off] : 0;
        __syncthreads();
        if (t < BKT_NODES) nx[t] += u;
        __syncthreads();
    }
    // pass 2: place (staging is L2-hot from pass 1)
#pragma unroll
    for (int r = 0; r < NREP; ++r) {
        const unsigned* sg = staging + ((size_t)b * NREP + r) * CAPR;
        for (int i = t; i < cnt_r[r]; i += 512) {
            unsigned e = sg[i];
            int sl = (int)(e >> 17);
            int rr = atomicAdd(&rk[sl], 1);  // LDS atomic
            ldst[nx[sl] - nh[sl] + rr] = (int)(e & 0x1FFFFu);
        }
    }
    __syncthreads();

    // ---- aggregation: 16 groups of 32 lanes; 4 edge slots x 8 sub-lanes ----
    int lane = t & 31;
    int grp = t >> 5;
    int slot = lane >> 3;
    int sub = lane & 7;
    int node0 = b << BKT_SHIFT;
    for (int ni = grp; ni < BKT_NODES; ni += 16) {
        int n = node0 + ni;
        if (n >= N) continue;
        int end = nx[ni];
        int beg = end - nh[ni];
        float4 qf = *(const float4*)(Q + (size_t)n * HS + sub * 4);
        float4 acc = make_float4(0.f, 0.f, 0.f, 0.f);
        float den = 0.f;
        // 1-deep pipelined edge loop: gather for j+4 issued before compute of j
        int d0 = (beg + slot < end) ? ldst[beg + slot] : 0;
        u16x8 kvc = *(const u16x8*)(KVb + (size_t)d0 * 64 + sub * 8);
        for (int j = beg; j < end; j += 4) {
            bool valid = (j + slot) < end;
            u16x8 kv = kvc;
            int jn = j + 4;
            if (jn < end) {  // group-uniform branch
                int dn = (jn + slot < end) ? ldst[jn + slot] : 0;
                kvc = *(const u16x8*)(KVb + (size_t)dn * 64 + sub * 8);
            }
            float p = qf.x * bf2f(kv[0]) + qf.y * bf2f(kv[1]) +
                      qf.z * bf2f(kv[2]) + qf.w * bf2f(kv[3]);
            p += __shfl_xor(p, 1, 32);
            p += __shfl_xor(p, 2, 32);
            p += __shfl_xor(p, 4, 32);
            float ex = valid ? __expf(p * 0.17677669529663687f) : 0.f;  // 1/sqrt(32)
            den += ex;
            acc.x += ex * bf2f(kv[4]);
            acc.y += ex * bf2f(kv[5]);
            acc.z += ex * bf2f(kv[6]);
            acc.w += ex * bf2f(kv[7]);
        }
        // sum the 4 edge slots (xor over slot bits 3,4)
#pragma unroll
        for (int off = 8; off <= 16; off <<= 1) {
            acc.x += __shfl_xor(acc.x, off, 32);
            acc.y += __shfl_xor(acc.y, off, 32);
            acc.z += __shfl_xor(acc.z, off, 32);
            acc.w += __shfl_xor(acc.w, off, 32);
            den += __shfl_xor(den, off, 32);
        }
        if (lane < 8) {
            float4 o = make_float4(0.f, 0.f, 0.f, 0.f);
            if (end > beg) {
                float rd = 1.f / den;
                o = make_float4(acc.x * rd, acc.y * rd, acc.z * rd, acc.w * rd);
            }
            *(float4*)(out + (size_t)n * HS + lane * 4) = o;
        }
    }
}

extern "C" void kernel_launch(void* const* d_in, const int* in_sizes, int n_in,
                              void* d_out, int out_size, void* d_ws, size_t ws_size,
                              hipStream_t stream) {
    const float* X  = (const float*)d_in[0];
    const int*   ei = (const int*)d_in[1];
    const float* Wq = (const float*)d_in[2];
    const float* Wk = (const float*)d_in[3];
    const float* Wv = (const float*)d_in[4];

    int N = in_sizes[0] / N_INPUT;
    int E = in_sizes[1] / 2;
    const int* src = ei;
    const int* dst = ei + E;

    // ws layout: Q[N*32] fp32 (12.8 MB); KVb[N*64] bf16 interleaved rows
    // (12.8 MB); Wp[3072] uint4 (48 KB); gtail[NREP*NBUCK_MAX];
    // staging[nbuck*NREP*CAPR] 4-B packed records (10.4 MB). No aliasing.
    float* ws = (float*)d_ws;
    float* Q = ws;
    unsigned short* KVb = (unsigned short*)(Q + (size_t)N * HS);
    uint4* Wp = (uint4*)(KVb + (size_t)N * 64);
    int* gtail = (int*)(Wp + 3072);
    unsigned* staging = (unsigned*)(gtail + NREP * NBUCK_MAX);
    float* out = (float*)d_out;

    int nbuck = (N + BKT_NODES - 1) >> BKT_SHIFT;  // 782
    int s1blocks = (E + EPB - 1) / EPB;            // 782
    int mtiles = (N + 15) / 16;
    int qblocks = (mtiles + 3) / 4;                // 1563

    prep_kernel<<<13, 256, 0, stream>>>(gtail, nbuck, Wq, Wk, Wv, Wp);
    mega_kernel<<<s1blocks + qblocks, 256, 0, stream>>>(
        X, Wp, src, dst, Q, KVb, gtail, staging, N, E, nbuck, s1blocks);
    s2_agg_kernel<<<nbuck, 512, 0, stream>>>(staging, gtail, Q, KVb, out, N);
}